// Round 4
// baseline (1257.334 us; speedup 1.0000x reference)
//
#include <hip/hip_runtime.h>

#define NN     6000
#define KNN    15
#define EPB    32          // edges per node = 2*(KNN+1)
#define HID    512
#define NLAYER 3
#define OUTDIM 12000       // NN * MODES
#define MB     32          // edge rows per block (1 node)

typedef _Float16 half8 __attribute__((ext_vector_type(8)));
typedef float    floatx4 __attribute__((ext_vector_type(4)));

// ---------- one-time: Wh fp32 [l][k][n] -> f16 transposed [l][n][k] ----------
__global__ void prep_weights(const float* __restrict__ Wh, _Float16* __restrict__ Wht)
{
    const int l  = blockIdx.z;
    const int k0 = blockIdx.y * 32, n0 = blockIdx.x * 32;
    __shared__ float tile[32][33];
    const int tx = threadIdx.x & 31, ty = threadIdx.x >> 5;   // 32 x 8
    const float* src = Wh + (size_t)l * HID * HID;
#pragma unroll
    for (int i = 0; i < 4; ++i)
        tile[ty + i * 8][tx] = src[(size_t)(k0 + ty + i * 8) * HID + n0 + tx];
    __syncthreads();
    _Float16* dst = Wht + (size_t)l * HID * HID;
#pragma unroll
    for (int i = 0; i < 4; ++i)
        dst[(size_t)(n0 + ty + i * 8) * HID + k0 + tx] = (_Float16)tile[tx][ty + i * 8];
}

// ---------- fused MLP (f16 MFMA) + scatter ----------
__global__ __launch_bounds__(256, 4)
void mlp_mfma_kernel(const float* __restrict__ CK,     // [NN, EPB, 3]
                     const float* __restrict__ W_in,   // [3, HID] fp32
                     const float* __restrict__ b_in,   // [HID]
                     const float* __restrict__ bh,     // [NLAYER, HID]
                     const float* __restrict__ W_out,  // [HID, 4] fp32
                     const float* __restrict__ b_out,  // [4]
                     const _Float16* __restrict__ Wht, // [NLAYER, HID(n), HID(k)] f16
                     float* __restrict__ out)          // pre-zeroed
{
    __shared__ __align__(16) _Float16 Ah[MB * HID];    // 32 KB, XOR-swizzled
    __shared__ float xs[MB * 3];

    const int t  = threadIdx.x;
    const int w  = t >> 6;          // wave 0..3 -> cols [w*128, w*128+128)
    const int ln = t & 63;
    const int lc = ln & 15;
    const int lg = ln >> 4;         // 0..3
    const int node = blockIdx.x;

    if (t < MB * 3) xs[t] = CK[(size_t)node * (EPB * 3) + t];

    // ---- input layer (fp32 VALU): cols j0, j0+1 for all 32 rows ----
    {
        const int j0 = t * 2;
        const float wi00 = W_in[0 * HID + j0], wi01 = W_in[0 * HID + j0 + 1];
        const float wi10 = W_in[1 * HID + j0], wi11 = W_in[1 * HID + j0 + 1];
        const float wi20 = W_in[2 * HID + j0], wi21 = W_in[2 * HID + j0 + 1];
        const float bi0 = b_in[j0], bi1 = b_in[j0 + 1];
        __syncthreads();
#pragma unroll 4
        for (int r = 0; r < MB; ++r) {
            const float x0 = xs[r * 3 + 0], x1 = xs[r * 3 + 1], x2 = xs[r * 3 + 2];
            float a0 = fmaf(x2, wi20, fmaf(x1, wi10, fmaf(x0, wi00, bi0)));
            float a1 = fmaf(x2, wi21, fmaf(x1, wi11, fmaf(x0, wi01, bi1)));
            a0 = fmaxf(a0, 0.f); a1 = fmaxf(a1, 0.f);
            const _Float16 h0 = (_Float16)a0, h1 = (_Float16)a1;
            unsigned u = (unsigned)__builtin_bit_cast(unsigned short, h0) |
                         ((unsigned)__builtin_bit_cast(unsigned short, h1) << 16);
            *(unsigned*)&Ah[r * HID + (j0 ^ ((r & 7) << 3))] = u;
        }
    }
    __syncthreads();

    // ---- hidden layers: MFMA, each wave computes 32x128 ----
    const int kbase = lg * 8;
    for (int layer = 0; layer < NLAYER; ++layer) {
        const _Float16* __restrict__ Wrow =
            Wht + (size_t)layer * HID * HID + (size_t)(w * 128 + lc) * HID;
        const float* __restrict__ bias = bh + layer * HID;

        floatx4 acc[2][8];
#pragma unroll
        for (int nf = 0; nf < 8; ++nf) {
            const float bv = bias[w * 128 + nf * 16 + lc];
#pragma unroll
            for (int mf = 0; mf < 2; ++mf)
                acc[mf][nf] = (floatx4){bv, bv, bv, bv};
        }

        for (int ks = 0; ks < HID; ks += 32) {
            const int kb = ks + kbase;
            half8 a[2], b[8];
#pragma unroll
            for (int mf = 0; mf < 2; ++mf) {
                const int r = mf * 16 + lc;
                a[mf] = *(const half8*)&Ah[r * HID + (kb ^ ((r & 7) << 3))];
            }
#pragma unroll
            for (int nf = 0; nf < 8; ++nf)
                b[nf] = *(const half8*)&Wrow[(size_t)(nf * 16) * HID + kb];
#pragma unroll
            for (int mf = 0; mf < 2; ++mf)
#pragma unroll
                for (int nf = 0; nf < 8; ++nf)
                    acc[mf][nf] = __builtin_amdgcn_mfma_f32_16x16x32_f16(
                        a[mf], b[nf], acc[mf][nf], 0, 0, 0);
        }
        __syncthreads();   // everyone done reading Ah
#pragma unroll
        for (int mf = 0; mf < 2; ++mf)
#pragma unroll
            for (int nf = 0; nf < 8; ++nf) {
                const int c = w * 128 + nf * 16 + lc;
#pragma unroll
                for (int j = 0; j < 4; ++j) {
                    const int r = mf * 16 + lg * 4 + j;
                    Ah[r * HID + (c ^ ((r & 7) << 3))] =
                        (_Float16)fmaxf(acc[mf][nf][j], 0.f);
                }
            }
        __syncthreads();   // new Ah visible
    }

    // ---- output layer (512 -> 4) + scatter-add ----
    {
        const int s  = t & 7;      // 8 lanes per edge
        const int rr = t >> 3;     // edge 0..31
        const int swzr = (rr & 7) << 3;
        float p0 = 0.f, p1 = 0.f, p2 = 0.f, p3 = 0.f;
        for (int i = 0; i < HID / 8; ++i) {
            const int k = s + i * 8;
            const float hv = (float)Ah[rr * HID + (k ^ swzr)];
            const floatx4 wv = *(const floatx4*)&W_out[k * 4];
            p0 = fmaf(hv, wv[0], p0);
            p1 = fmaf(hv, wv[1], p1);
            p2 = fmaf(hv, wv[2], p2);
            p3 = fmaf(hv, wv[3], p3);
        }
#pragma unroll
        for (int m = 1; m < 8; m <<= 1) {
            p0 += __shfl_xor(p0, m, 64);
            p1 += __shfl_xor(p1, m, 64);
            p2 += __shfl_xor(p2, m, 64);
            p3 += __shfl_xor(p3, m, 64);
        }
        if (s == 0) {
            int c = node + rr - KNN;
            c = c < 0 ? 0 : (c > NN - 1 ? NN - 1 : c);
            const size_t row0 = (size_t)(node * 2);
            const size_t col0 = (size_t)(c * 2);
            atomicAdd(&out[(row0 + 0) * OUTDIM + col0 + 0], p0 + b_out[0]);
            atomicAdd(&out[(row0 + 0) * OUTDIM + col0 + 1], p1 + b_out[1]);
            atomicAdd(&out[(row0 + 1) * OUTDIM + col0 + 0], p2 + b_out[2]);
            atomicAdd(&out[(row0 + 1) * OUTDIM + col0 + 1], p3 + b_out[3]);
        }
    }
}

extern "C" void kernel_launch(void* const* d_in, const int* in_sizes, int n_in,
                              void* d_out, int out_size, void* d_ws, size_t ws_size,
                              hipStream_t stream) {
    const float* CK    = (const float*)d_in[0];
    const float* W_in  = (const float*)d_in[1];
    const float* b_in  = (const float*)d_in[2];
    const float* Wh    = (const float*)d_in[3];
    const float* bh    = (const float*)d_in[4];
    const float* W_out = (const float*)d_in[5];
    const float* b_out = (const float*)d_in[6];
    float* out = (float*)d_out;

    _Float16* Wht = (_Float16*)d_ws;   // 3*512*512 f16 = 1.5 MB

    prep_weights<<<dim3(HID / 32, HID / 32, NLAYER), 256, 0, stream>>>(Wh, Wht);
    hipMemsetAsync(out, 0, (size_t)out_size * sizeof(float), stream);
    mlp_mfma_kernel<<<NN, 256, 0, stream>>>(CK, W_in, b_in, bh, W_out, b_out, Wht, out);
}

// Round 5
// 892.853 us; speedup vs baseline: 1.4082x; 1.4082x over previous
//
#include <hip/hip_runtime.h>

#define NN     6000
#define KNN    15
#define EPB    32          // edges per node = 2*(KNN+1)
#define HID    512
#define NLAYER 3
#define OUTDIM 12000       // NN * MODES
#define MB     64          // edge rows per block (2 nodes)

typedef _Float16 half8 __attribute__((ext_vector_type(8)));
typedef float    floatx4 __attribute__((ext_vector_type(4)));

// ---------- one-time: Wh fp32 [l][k][n] -> f16 transposed [l][n][k] ----------
__global__ void prep_weights(const float* __restrict__ Wh, _Float16* __restrict__ Wht)
{
    const int l  = blockIdx.z;
    const int k0 = blockIdx.y * 32, n0 = blockIdx.x * 32;
    __shared__ float tile[32][33];
    const int tx = threadIdx.x & 31, ty = threadIdx.x >> 5;   // 32 x 8
    const float* src = Wh + (size_t)l * HID * HID;
#pragma unroll
    for (int i = 0; i < 4; ++i)
        tile[ty + i * 8][tx] = src[(size_t)(k0 + ty + i * 8) * HID + n0 + tx];
    __syncthreads();
    _Float16* dst = Wht + (size_t)l * HID * HID;
#pragma unroll
    for (int i = 0; i < 4; ++i)
        dst[(size_t)(n0 + ty + i * 8) * HID + k0 + tx] = (_Float16)tile[tx][ty + i * 8];
}

// ---------- fused MLP (f16 MFMA) -> compact vals (no output touch) ----------
__global__ __launch_bounds__(256, 2)
void mlp_mfma_kernel(const float* __restrict__ CK,     // [NN, EPB, 3]
                     const float* __restrict__ W_in,   // [3, HID] fp32
                     const float* __restrict__ b_in,   // [HID]
                     const float* __restrict__ bh,     // [NLAYER, HID]
                     const float* __restrict__ W_out,  // [HID, 4] fp32
                     const float* __restrict__ b_out,  // [4]
                     const _Float16* __restrict__ Wht, // [NLAYER, HID(n), HID(k)] f16
                     float4* __restrict__ vals)        // [NN, EPB]
{
    __shared__ __align__(16) _Float16 Ah[MB * HID];    // 64 KB, XOR-swizzled
    __shared__ float xs[MB * 3];

    const int t  = threadIdx.x;
    const int w  = t >> 6;          // wave 0..3 -> cols [w*128, w*128+128)
    const int ln = t & 63;
    const int lc = ln & 15;
    const int lg = ln >> 4;         // 0..3
    const int node0 = blockIdx.x * 2;

    if (t < MB * 3) xs[t] = CK[(size_t)node0 * (EPB * 3) + t];

    // ---- input layer (fp32 VALU) ----
    {
        const int j0 = t * 2;
        const float wi00 = W_in[0 * HID + j0], wi01 = W_in[0 * HID + j0 + 1];
        const float wi10 = W_in[1 * HID + j0], wi11 = W_in[1 * HID + j0 + 1];
        const float wi20 = W_in[2 * HID + j0], wi21 = W_in[2 * HID + j0 + 1];
        const float bi0 = b_in[j0], bi1 = b_in[j0 + 1];
        __syncthreads();
#pragma unroll 4
        for (int r = 0; r < MB; ++r) {
            const float x0 = xs[r * 3 + 0], x1 = xs[r * 3 + 1], x2 = xs[r * 3 + 2];
            float a0 = fmaf(x2, wi20, fmaf(x1, wi10, fmaf(x0, wi00, bi0)));
            float a1 = fmaf(x2, wi21, fmaf(x1, wi11, fmaf(x0, wi01, bi1)));
            a0 = fmaxf(a0, 0.f); a1 = fmaxf(a1, 0.f);
            const _Float16 h0 = (_Float16)a0, h1 = (_Float16)a1;
            unsigned u = (unsigned)__builtin_bit_cast(unsigned short, h0) |
                         ((unsigned)__builtin_bit_cast(unsigned short, h1) << 16);
            *(unsigned*)&Ah[r * HID + (j0 ^ ((r & 7) << 3))] = u;
        }
    }
    __syncthreads();

    // ---- hidden layers: MFMA, each wave computes 64x128 ----
    const int kbase = lg * 8;
    for (int layer = 0; layer < NLAYER; ++layer) {
        const _Float16* __restrict__ Wrow =
            Wht + (size_t)layer * HID * HID + (size_t)(w * 128 + lc) * HID;
        const float* __restrict__ bias = bh + layer * HID;

        floatx4 acc[4][8];
#pragma unroll
        for (int nf = 0; nf < 8; ++nf) {
            const float bv = bias[w * 128 + nf * 16 + lc];
#pragma unroll
            for (int mf = 0; mf < 4; ++mf)
                acc[mf][nf] = (floatx4){bv, bv, bv, bv};
        }

        for (int ks = 0; ks < HID; ks += 32) {
            const int kb = ks + kbase;
            half8 a[4], b[8];
#pragma unroll
            for (int mf = 0; mf < 4; ++mf) {
                const int r = mf * 16 + lc;
                a[mf] = *(const half8*)&Ah[r * HID + (kb ^ ((r & 7) << 3))];
            }
#pragma unroll
            for (int nf = 0; nf < 8; ++nf)
                b[nf] = *(const half8*)&Wrow[(size_t)(nf * 16) * HID + kb];
#pragma unroll
            for (int mf = 0; mf < 4; ++mf)
#pragma unroll
                for (int nf = 0; nf < 8; ++nf)
                    acc[mf][nf] = __builtin_amdgcn_mfma_f32_16x16x32_f16(
                        a[mf], b[nf], acc[mf][nf], 0, 0, 0);
        }
        __syncthreads();   // everyone done reading Ah
#pragma unroll
        for (int mf = 0; mf < 4; ++mf)
#pragma unroll
            for (int nf = 0; nf < 8; ++nf) {
                const int c = w * 128 + nf * 16 + lc;
#pragma unroll
                for (int j = 0; j < 4; ++j) {
                    const int r = mf * 16 + lg * 4 + j;
                    Ah[r * HID + (c ^ ((r & 7) << 3))] =
                        (_Float16)fmaxf(acc[mf][nf][j], 0.f);
                }
            }
        __syncthreads();   // new Ah visible
    }

    // ---- output layer (512 -> 4), write compact vals ----
    {
        const int s  = t & 7;
        const int e0 = t >> 3;
        const float4 bo = *(const float4*)b_out;
#pragma unroll
        for (int hf = 0; hf < 2; ++hf) {
            const int rr = e0 + hf * 32;
            const int swzr = (rr & 7) << 3;
            float p0 = 0.f, p1 = 0.f, p2 = 0.f, p3 = 0.f;
            for (int i = 0; i < HID / 8; ++i) {
                const int k = s + i * 8;
                const float hv = (float)Ah[rr * HID + (k ^ swzr)];
                const floatx4 wv = *(const floatx4*)&W_out[k * 4];
                p0 = fmaf(hv, wv[0], p0);
                p1 = fmaf(hv, wv[1], p1);
                p2 = fmaf(hv, wv[2], p2);
                p3 = fmaf(hv, wv[3], p3);
            }
#pragma unroll
            for (int m = 1; m < 8; m <<= 1) {
                p0 += __shfl_xor(p0, m, 64);
                p1 += __shfl_xor(p1, m, 64);
                p2 += __shfl_xor(p2, m, 64);
                p3 += __shfl_xor(p3, m, 64);
            }
            if (s == 0) {
                // node = node0 + (rr>>5), edge = rr&31 -> linear index node0*EPB + rr
                vals[(size_t)node0 * EPB + rr] =
                    make_float4(p0 + bo.x, p1 + bo.y, p2 + bo.z, p3 + bo.w);
            }
        }
    }
}

// ---------- writer: zeros + band accumulation, full 576 MB streamed ----------
__global__ __launch_bounds__(256, 8)
void write_out(const float4* __restrict__ vals, float* __restrict__ out)
{
    const int n = blockIdx.x;
    const int t = threadIdx.x;
    __shared__ float4 v[EPB];
    __shared__ float  band[2][2 * EPB];   // [mi][float-col within band], width<=64

    if (t < EPB) v[t] = vals[(size_t)n * EPB + t];
    const int cmin  = (n - KNN < 0) ? 0 : n - KNN;
    const int cmax  = (n + KNN + 1 > NN - 1) ? NN - 1 : n + KNN + 1;
    const int width = cmax - cmin + 1;    // node-cols in band
    __syncthreads();

    if (t < width) {
        const int c = cmin + t;
        int e_lo, e_hi;
        if (c == 0)           { e_lo = 0;                  e_hi = KNN - n; }        // clip-below dups
        else if (c == NN - 1) { e_lo = (NN - 1) - n + KNN; e_hi = EPB - 1; }        // clip-above dups
        else                  { e_lo = e_hi = c - n + KNN; }
        float s0 = 0.f, s1 = 0.f, s2 = 0.f, s3 = 0.f;
        for (int e = e_lo; e <= e_hi; ++e) {
            const float4 pv = v[e];
            s0 += pv.x; s1 += pv.y; s2 += pv.z; s3 += pv.w;
        }
        band[0][2 * t] = s0; band[0][2 * t + 1] = s1;
        band[1][2 * t] = s2; band[1][2 * t + 1] = s3;
    }
    __syncthreads();

    const int j0 = 2 * cmin;              // first nonzero float col
    const int w2 = 2 * width;
#pragma unroll
    for (int mi = 0; mi < 2; ++mi) {
        float* rowp = out + (size_t)(2 * n + mi) * OUTDIM;
        for (int q = t; q < OUTDIM / 4; q += 256) {
            const int j = 4 * q;
            float4 o;
            o.x = ((unsigned)(j + 0 - j0) < (unsigned)w2) ? band[mi][j + 0 - j0] : 0.f;
            o.y = ((unsigned)(j + 1 - j0) < (unsigned)w2) ? band[mi][j + 1 - j0] : 0.f;
            o.z = ((unsigned)(j + 2 - j0) < (unsigned)w2) ? band[mi][j + 2 - j0] : 0.f;
            o.w = ((unsigned)(j + 3 - j0) < (unsigned)w2) ? band[mi][j + 3 - j0] : 0.f;
            *(float4*)(rowp + j) = o;     // full-line coalesced stores
        }
    }
}

extern "C" void kernel_launch(void* const* d_in, const int* in_sizes, int n_in,
                              void* d_out, int out_size, void* d_ws, size_t ws_size,
                              hipStream_t stream) {
    const float* CK    = (const float*)d_in[0];
    const float* W_in  = (const float*)d_in[1];
    const float* b_in  = (const float*)d_in[2];
    const float* Wh    = (const float*)d_in[3];
    const float* bh    = (const float*)d_in[4];
    const float* W_out = (const float*)d_in[5];
    const float* b_out = (const float*)d_in[6];
    float* out = (float*)d_out;

    _Float16* Wht  = (_Float16*)d_ws;                          // 1.5 MB
    float4*   vals = (float4*)((char*)d_ws + (size_t)3 * HID * HID * sizeof(_Float16)); // 3 MB

    prep_weights<<<dim3(HID / 32, HID / 32, NLAYER), 256, 0, stream>>>(Wh, Wht);
    mlp_mfma_kernel<<<NN / 2, 256, 0, stream>>>(CK, W_in, b_in, bh, W_out, b_out, Wht, vals);
    write_out<<<NN, 256, 0, stream>>>(vals, out);
}

// Round 7
// 876.259 us; speedup vs baseline: 1.4349x; 1.0189x over previous
//
#include <hip/hip_runtime.h>

#define NN     6000
#define KNN    15
#define EPB    32          // edges per node = 2*(KNN+1)
#define HID    512
#define NLAYER 3
#define OUTDIM 12000       // NN * MODES
#define MB     64          // edge rows per block (2 nodes)
#define NTH    512         // 8 waves

typedef _Float16 half8 __attribute__((ext_vector_type(8)));
typedef float    floatx4 __attribute__((ext_vector_type(4)));

// ---------- one-time: Wh fp32 [l][k][n] -> f16 transposed [l][n][k] ----------
__global__ void prep_weights(const float* __restrict__ Wh, _Float16* __restrict__ Wht)
{
    const int l  = blockIdx.z;
    const int k0 = blockIdx.y * 32, n0 = blockIdx.x * 32;
    __shared__ float tile[32][33];
    const int tx = threadIdx.x & 31, ty = threadIdx.x >> 5;   // 32 x 8
    const float* src = Wh + (size_t)l * HID * HID;
#pragma unroll
    for (int i = 0; i < 4; ++i)
        tile[ty + i * 8][tx] = src[(size_t)(k0 + ty + i * 8) * HID + n0 + tx];
    __syncthreads();
    _Float16* dst = Wht + (size_t)l * HID * HID;
#pragma unroll
    for (int i = 0; i < 4; ++i)
        dst[(size_t)(n0 + ty + i * 8) * HID + k0 + tx] = (_Float16)tile[tx][ty + i * 8];
}

// ---------- fused MLP (f16 MFMA) -> compact vals ----------
// 8 waves; wave w computes rows 0..63 x cols [w*64, w*64+64): acc 4x4 frags (64 AGPR)
__global__ __launch_bounds__(NTH, 4)
void mlp_mfma_kernel(const float* __restrict__ CK,     // [NN, EPB, 3]
                     const float* __restrict__ W_in,   // [3, HID] fp32
                     const float* __restrict__ b_in,   // [HID]
                     const float* __restrict__ bh,     // [NLAYER, HID]
                     const float* __restrict__ W_out,  // [HID, 4] fp32
                     const float* __restrict__ b_out,  // [4]
                     const _Float16* __restrict__ Wht, // [NLAYER, HID(n), HID(k)] f16
                     float4* __restrict__ vals)        // [NN, EPB]
{
    __shared__ __align__(16) _Float16 Ah[MB * HID];    // 64 KB, XOR-swizzled
    __shared__ float xs[MB * 3];

    const int t  = threadIdx.x;
    const int w  = t >> 6;          // wave 0..7 -> cols [w*64, w*64+64)
    const int ln = t & 63;
    const int lc = ln & 15;
    const int lg = ln >> 4;         // 0..3
    const int node0 = blockIdx.x * 2;

    if (t < MB * 3) xs[t] = CK[(size_t)node0 * (EPB * 3) + t];

    // ---- input layer (fp32 VALU): one column per thread ----
    {
        const int j0 = t;           // 0..511
        const float wi0 = W_in[j0], wi1 = W_in[HID + j0], wi2 = W_in[2 * HID + j0];
        const float bi  = b_in[j0];
        __syncthreads();
#pragma unroll 8
        for (int r = 0; r < MB; ++r) {
            float a = fmaf(xs[r * 3 + 2], wi2,
                      fmaf(xs[r * 3 + 1], wi1,
                      fmaf(xs[r * 3 + 0], wi0, bi)));
            Ah[r * HID + (j0 ^ ((r & 7) << 3))] = (_Float16)fmaxf(a, 0.f);
        }
    }
    __syncthreads();

    // ---- hidden layers ----
    const int kbase = lg * 8;
    const int swzA  = (lc & 7) << 3;          // row swizzle: (mf*16+lc)&7 == lc&7
    for (int layer = 0; layer < NLAYER; ++layer) {
        const _Float16* __restrict__ Wrow =
            Wht + (size_t)layer * HID * HID + (size_t)(w * 64 + lc) * HID;
        const float* __restrict__ bias = bh + layer * HID;

        floatx4 acc[4][4];
#pragma unroll
        for (int nf = 0; nf < 4; ++nf) {
            const float bv = bias[w * 64 + nf * 16 + lc];
#pragma unroll
            for (int mf = 0; mf < 4; ++mf)
                acc[mf][nf] = (floatx4){bv, bv, bv, bv};
        }

        for (int ks = 0; ks < HID; ks += 32) {
            const int kb = ks + kbase;
            half8 a[4], b[4];
#pragma unroll
            for (int mf = 0; mf < 4; ++mf)
                a[mf] = *(const half8*)&Ah[(mf * 16 + lc) * HID + (kb ^ swzA)];
#pragma unroll
            for (int nf = 0; nf < 4; ++nf)
                b[nf] = *(const half8*)&Wrow[(size_t)(nf * 16) * HID + kb];
#pragma unroll
            for (int mf = 0; mf < 4; ++mf)
#pragma unroll
                for (int nf = 0; nf < 4; ++nf)
                    acc[mf][nf] = __builtin_amdgcn_mfma_f32_16x16x32_f16(
                        a[mf], b[nf], acc[mf][nf], 0, 0, 0);
        }
        __syncthreads();   // everyone done reading Ah
#pragma unroll
        for (int mf = 0; mf < 4; ++mf)
#pragma unroll
            for (int nf = 0; nf < 4; ++nf) {
                const int c = w * 64 + nf * 16 + lc;
#pragma unroll
                for (int j = 0; j < 4; ++j) {
                    const int r = mf * 16 + lg * 4 + j;
                    Ah[r * HID + (c ^ ((r & 7) << 3))] =
                        (_Float16)fmaxf(acc[mf][nf][j], 0.f);
                }
            }
        __syncthreads();   // new Ah visible
    }

    // ---- output layer (512 -> 4), write compact vals ----
    {
        const int s  = t & 7;       // 8 lanes per edge
        const int rr = t >> 3;      // 0..63: all 64 edges in one pass
        const int swzr = (rr & 7) << 3;
        const float4 bo = *(const float4*)b_out;
        float p0 = 0.f, p1 = 0.f, p2 = 0.f, p3 = 0.f;
        for (int i = 0; i < HID / 8; ++i) {
            const int k = s + i * 8;
            const float hv = (float)Ah[rr * HID + (k ^ swzr)];
            const floatx4 wv = *(const floatx4*)&W_out[k * 4];
            p0 = fmaf(hv, wv[0], p0);
            p1 = fmaf(hv, wv[1], p1);
            p2 = fmaf(hv, wv[2], p2);
            p3 = fmaf(hv, wv[3], p3);
        }
#pragma unroll
        for (int m = 1; m < 8; m <<= 1) {
            p0 += __shfl_xor(p0, m, 64);
            p1 += __shfl_xor(p1, m, 64);
            p2 += __shfl_xor(p2, m, 64);
            p3 += __shfl_xor(p3, m, 64);
        }
        if (s == 0)
            vals[(size_t)node0 * EPB + rr] =
                make_float4(p0 + bo.x, p1 + bo.y, p2 + bo.z, p3 + bo.w);
    }
}

// ---------- writer: zeros + band accumulation, nt stores (L2 no-allocate) ----------
__global__ __launch_bounds__(256, 8)
void write_out(const float4* __restrict__ vals, float* __restrict__ out)
{
    const int n = blockIdx.x;
    const int t = threadIdx.x;
    __shared__ float4 v[EPB];
    __shared__ float  band[2][2 * EPB];   // [mi][float-col within band], width<=64

    if (t < EPB) v[t] = vals[(size_t)n * EPB + t];
    const int cmin  = (n - KNN < 0) ? 0 : n - KNN;
    const int cmax  = (n + KNN + 1 > NN - 1) ? NN - 1 : n + KNN + 1;
    const int width = cmax - cmin + 1;    // node-cols in band
    __syncthreads();

    if (t < width) {
        const int c = cmin + t;
        int e_lo, e_hi;
        if (c == 0)           { e_lo = 0;                  e_hi = KNN - n; }        // clip-below dups
        else if (c == NN - 1) { e_lo = (NN - 1) - n + KNN; e_hi = EPB - 1; }        // clip-above dups
        else                  { e_lo = e_hi = c - n + KNN; }
        float s0 = 0.f, s1 = 0.f, s2 = 0.f, s3 = 0.f;
        for (int e = e_lo; e <= e_hi; ++e) {
            const float4 pv = v[e];
            s0 += pv.x; s1 += pv.y; s2 += pv.z; s3 += pv.w;
        }
        band[0][2 * t] = s0; band[0][2 * t + 1] = s1;
        band[1][2 * t] = s2; band[1][2 * t + 1] = s3;
    }
    __syncthreads();

    const int j0 = 2 * cmin;              // first nonzero float col
    const int w2 = 2 * width;
#pragma unroll
    for (int mi = 0; mi < 2; ++mi) {
        float* rowp = out + (size_t)(2 * n + mi) * OUTDIM;
        for (int q = t; q < OUTDIM / 4; q += 256) {
            const int j = 4 * q;
            floatx4 o;
            o[0] = ((unsigned)(j + 0 - j0) < (unsigned)w2) ? band[mi][j + 0 - j0] : 0.f;
            o[1] = ((unsigned)(j + 1 - j0) < (unsigned)w2) ? band[mi][j + 1 - j0] : 0.f;
            o[2] = ((unsigned)(j + 2 - j0) < (unsigned)w2) ? band[mi][j + 2 - j0] : 0.f;
            o[3] = ((unsigned)(j + 3 - j0) < (unsigned)w2) ? band[mi][j + 3 - j0] : 0.f;
            __builtin_nontemporal_store(o, (floatx4*)(rowp + j));   // bypass L2 pollution
        }
    }
}

extern "C" void kernel_launch(void* const* d_in, const int* in_sizes, int n_in,
                              void* d_out, int out_size, void* d_ws, size_t ws_size,
                              hipStream_t stream) {
    const float* CK    = (const float*)d_in[0];
    const float* W_in  = (const float*)d_in[1];
    const float* b_in  = (const float*)d_in[2];
    const float* Wh    = (const float*)d_in[3];
    const float* bh    = (const float*)d_in[4];
    const float* W_out = (const float*)d_in[5];
    const float* b_out = (const float*)d_in[6];
    float* out = (float*)d_out;

    _Float16* Wht  = (_Float16*)d_ws;                          // 1.5 MB
    float4*   vals = (float4*)((char*)d_ws + (size_t)3 * HID * HID * sizeof(_Float16)); // 3 MB

    prep_weights<<<dim3(HID / 32, HID / 32, NLAYER), 256, 0, stream>>>(Wh, Wht);
    mlp_mfma_kernel<<<NN / 2, NTH, 0, stream>>>(CK, W_in, b_in, bh, W_out, b_out, Wht, vals);
    write_out<<<NN, 256, 0, stream>>>(vals, out);
}

// Round 8
// 640.898 us; speedup vs baseline: 1.9618x; 1.3672x over previous
//
#include <hip/hip_runtime.h>

#define NN     6000
#define KNN    15
#define EPB    32          // edges per node = 2*(KNN+1)
#define HID    512
#define NLAYER 3
#define OUTDIM 12000       // NN * MODES
#define MB     64          // edge rows per block (2 nodes)
#define NTH    512         // 8 waves

typedef _Float16 half8 __attribute__((ext_vector_type(8)));
typedef float    floatx4 __attribute__((ext_vector_type(4)));

// ---------- one-time: Wh fp32 [l][k][n] -> MFMA-fragment-tiled f16 ----------
// Wt = [l][kt=16][nt=32] x 1KB blocks; within a block, lane ln (0..63) holds
// half8 { W[kt*32 + (ln>>4)*8 + j][nt*16 + (ln&15)] , j=0..7 }  (lane-linear).
__global__ void prep_weights(const float* __restrict__ Wh, _Float16* __restrict__ Wt)
{
    const int blk = blockIdx.x;          // ((l*16)+kt)*32 + nt,  0..1535
    const int ln  = threadIdx.x;         // 0..63
    const int nt  = blk & 31;
    const int kt  = (blk >> 5) & 15;
    const int l   = blk >> 9;
    const int lc  = ln & 15, lg = ln >> 4;
    const float* src = Wh + (size_t)l * HID * HID
                          + (size_t)(kt * 32 + lg * 8) * HID + nt * 16 + lc;
    half8 v;
#pragma unroll
    for (int j = 0; j < 8; ++j) v[j] = (_Float16)src[(size_t)j * HID];
    *(half8*)(Wt + (size_t)blk * 512 + ln * 8) = v;
}

// ---------- fused MLP (f16 MFMA) -> compact vals ----------
// 8 waves; wave w computes rows 0..63 x cols [w*64, w*64+64): acc 4x4 frags
__global__ __launch_bounds__(NTH, 4)
void mlp_mfma_kernel(const float* __restrict__ CK,     // [NN, EPB, 3]
                     const float* __restrict__ W_in,   // [3, HID] fp32
                     const float* __restrict__ b_in,   // [HID]
                     const float* __restrict__ bh,     // [NLAYER, HID]
                     const float* __restrict__ W_out,  // [HID, 4] fp32
                     const float* __restrict__ b_out,  // [4]
                     const _Float16* __restrict__ Wt,  // tiled weights (see prep)
                     float4* __restrict__ vals)        // [NN, EPB]
{
    __shared__ __align__(16) _Float16 Ah[MB * HID];    // 64 KB, XOR-swizzled
    __shared__ float xs[MB * 3];

    const int t  = threadIdx.x;
    const int w  = t >> 6;          // wave 0..7 -> cols [w*64, w*64+64)
    const int ln = t & 63;
    const int lc = ln & 15;
    const int lg = ln >> 4;         // 0..3
    const int node0 = blockIdx.x * 2;

    if (t < MB * 3) xs[t] = CK[(size_t)node0 * (EPB * 3) + t];

    // ---- input layer (fp32 VALU): one column per thread ----
    {
        const int j0 = t;           // 0..511
        const float wi0 = W_in[j0], wi1 = W_in[HID + j0], wi2 = W_in[2 * HID + j0];
        const float bi  = b_in[j0];
        __syncthreads();
#pragma unroll 8
        for (int r = 0; r < MB; ++r) {
            float a = fmaf(xs[r * 3 + 2], wi2,
                      fmaf(xs[r * 3 + 1], wi1,
                      fmaf(xs[r * 3 + 0], wi0, bi)));
            Ah[r * HID + (j0 ^ ((r & 7) << 3))] = (_Float16)fmaxf(a, 0.f);
        }
    }
    __syncthreads();

    // ---- hidden layers ----
    const int kbase = lg * 8;
    const int swzA  = (lc & 7) << 3;          // row swizzle: (mf*16+lc)&7 == lc&7
    for (int layer = 0; layer < NLAYER; ++layer) {
        const _Float16* __restrict__ Wl = Wt + (size_t)layer * (16 * 32 * 512);
        const float* __restrict__ bias = bh + layer * HID;

        floatx4 acc[4][4];
#pragma unroll
        for (int nf = 0; nf < 4; ++nf) {
            const float bv = bias[w * 64 + nf * 16 + lc];
#pragma unroll
            for (int mf = 0; mf < 4; ++mf)
                acc[mf][nf] = (floatx4){bv, bv, bv, bv};
        }

        for (int kt = 0; kt < 16; ++kt) {
            const int kb = kt * 32 + kbase;
            // wave w's 4 b-frags this k-step: 4 consecutive 1KB blocks (4KB contiguous)
            const _Float16* bp = Wl + ((size_t)(kt * 32 + w * 4) << 9) + ln * 8;
            half8 a[4], b[4];
#pragma unroll
            for (int mf = 0; mf < 4; ++mf)
                a[mf] = *(const half8*)&Ah[(mf * 16 + lc) * HID + (kb ^ swzA)];
#pragma unroll
            for (int nf = 0; nf < 4; ++nf)
                b[nf] = *(const half8*)(bp + (size_t)nf * 512);
#pragma unroll
            for (int mf = 0; mf < 4; ++mf)
#pragma unroll
                for (int nf = 0; nf < 4; ++nf)
                    acc[mf][nf] = __builtin_amdgcn_mfma_f32_16x16x32_f16(
                        a[mf], b[nf], acc[mf][nf], 0, 0, 0);
        }
        __syncthreads();   // everyone done reading Ah
#pragma unroll
        for (int mf = 0; mf < 4; ++mf)
#pragma unroll
            for (int nf = 0; nf < 4; ++nf) {
                const int c = w * 64 + nf * 16 + lc;
#pragma unroll
                for (int j = 0; j < 4; ++j) {
                    const int r = mf * 16 + lg * 4 + j;
                    Ah[r * HID + (c ^ ((r & 7) << 3))] =
                        (_Float16)fmaxf(acc[mf][nf][j], 0.f);
                }
            }
        __syncthreads();   // new Ah visible
    }

    // ---- output layer (512 -> 4), write compact vals ----
    {
        const int s  = t & 7;       // 8 lanes per edge
        const int rr = t >> 3;      // 0..63: all 64 edges in one pass
        const int swzr = (rr & 7) << 3;
        const float4 bo = *(const float4*)b_out;
        float p0 = 0.f, p1 = 0.f, p2 = 0.f, p3 = 0.f;
        for (int i = 0; i < HID / 8; ++i) {
            const int k = s + i * 8;
            const float hv = (float)Ah[rr * HID + (k ^ swzr)];
            const floatx4 wv = *(const floatx4*)&W_out[k * 4];
            p0 = fmaf(hv, wv[0], p0);
            p1 = fmaf(hv, wv[1], p1);
            p2 = fmaf(hv, wv[2], p2);
            p3 = fmaf(hv, wv[3], p3);
        }
#pragma unroll
        for (int m = 1; m < 8; m <<= 1) {
            p0 += __shfl_xor(p0, m, 64);
            p1 += __shfl_xor(p1, m, 64);
            p2 += __shfl_xor(p2, m, 64);
            p3 += __shfl_xor(p3, m, 64);
        }
        if (s == 0)
            vals[(size_t)node0 * EPB + rr] =
                make_float4(p0 + bo.x, p1 + bo.y, p2 + bo.z, p3 + bo.w);
    }
}

// ---------- writer: zeros + band accumulation, nt stores ----------
__global__ __launch_bounds__(256, 8)
void write_out(const float4* __restrict__ vals, float* __restrict__ out)
{
    const int n = blockIdx.x;
    const int t = threadIdx.x;
    __shared__ float4 v[EPB];
    __shared__ float  band[2][2 * EPB];   // [mi][float-col within band], width<=64

    if (t < EPB) v[t] = vals[(size_t)n * EPB + t];
    const int cmin  = (n - KNN < 0) ? 0 : n - KNN;
    const int cmax  = (n + KNN + 1 > NN - 1) ? NN - 1 : n + KNN + 1;
    const int width = cmax - cmin + 1;    // node-cols in band
    __syncthreads();

    if (t < width) {
        const int c = cmin + t;
        int e_lo, e_hi;
        if (c == 0)           { e_lo = 0;                  e_hi = KNN - n; }
        else if (c == NN - 1) { e_lo = (NN - 1) - n + KNN; e_hi = EPB - 1; }
        else                  { e_lo = e_hi = c - n + KNN; }
        float s0 = 0.f, s1 = 0.f, s2 = 0.f, s3 = 0.f;
        for (int e = e_lo; e <= e_hi; ++e) {
            const float4 pv = v[e];
            s0 += pv.x; s1 += pv.y; s2 += pv.z; s3 += pv.w;
        }
        band[0][2 * t] = s0; band[0][2 * t + 1] = s1;
        band[1][2 * t] = s2; band[1][2 * t + 1] = s3;
    }
    __syncthreads();

    const int j0 = 2 * cmin;              // first nonzero float col
    const int w2 = 2 * width;
#pragma unroll
    for (int mi = 0; mi < 2; ++mi) {
        float* rowp = out + (size_t)(2 * n + mi) * OUTDIM;
        for (int q = t; q < OUTDIM / 4; q += 256) {
            const int j = 4 * q;
            floatx4 o;
            o[0] = ((unsigned)(j + 0 - j0) < (unsigned)w2) ? band[mi][j + 0 - j0] : 0.f;
            o[1] = ((unsigned)(j + 1 - j0) < (unsigned)w2) ? band[mi][j + 1 - j0] : 0.f;
            o[2] = ((unsigned)(j + 2 - j0) < (unsigned)w2) ? band[mi][j + 2 - j0] : 0.f;
            o[3] = ((unsigned)(j + 3 - j0) < (unsigned)w2) ? band[mi][j + 3 - j0] : 0.f;
            __builtin_nontemporal_store(o, (floatx4*)(rowp + j));
        }
    }
}

extern "C" void kernel_launch(void* const* d_in, const int* in_sizes, int n_in,
                              void* d_out, int out_size, void* d_ws, size_t ws_size,
                              hipStream_t stream) {
    const float* CK    = (const float*)d_in[0];
    const float* W_in  = (const float*)d_in[1];
    const float* b_in  = (const float*)d_in[2];
    const float* Wh    = (const float*)d_in[3];
    const float* bh    = (const float*)d_in[4];
    const float* W_out = (const float*)d_in[5];
    const float* b_out = (const float*)d_in[6];
    float* out = (float*)d_out;

    _Float16* Wt   = (_Float16*)d_ws;                          // 1.5 MB tiled
    float4*   vals = (float4*)((char*)d_ws + (size_t)3 * HID * HID * sizeof(_Float16)); // 3 MB

    prep_weights<<<NLAYER * 16 * 32, 64, 0, stream>>>(Wh, Wt);
    mlp_mfma_kernel<<<NN / 2, NTH, 0, stream>>>(CK, W_in, b_in, bh, W_out, b_out, Wt, vals);
    write_out<<<NN, 256, 0, stream>>>(vals, out);
}